// Round 1
// baseline (3580.301 us; speedup 1.0000x reference)
//
#include <hip/hip_runtime.h>
#include <math.h>

constexpr int N_NODES = 4096;
constexpr int N_EDGES = 65536;
constexpr int D_INF   = 64;
constexpr int H       = 128;
constexpr int T       = 8;
constexpr int B       = 8;
constexpr int M       = B * N_NODES;   // 32768 rows per GEMM

// ---------------- CSR build ----------------

__global__ void k_count(const int* __restrict__ dst, int* __restrict__ cnt) {
  int e = blockIdx.x * blockDim.x + threadIdx.x;
  if (e < N_EDGES) atomicAdd(&cnt[dst[e]], 1);
}

__global__ void k_dinv(const int* __restrict__ cnt, float* __restrict__ dinv) {
  int n = blockIdx.x * blockDim.x + threadIdx.x;
  if (n < N_NODES) dinv[n] = 1.0f / sqrtf((float)cnt[n] + 2.0f);
}

// single block, 1024 threads, exclusive scan of 4096 counts -> rowptr[0..4096]
__global__ void k_scan(const int* __restrict__ cnt, int* __restrict__ rowptr) {
  __shared__ int sums[1024];
  int t = threadIdx.x;
  int v0 = cnt[4*t+0], v1 = cnt[4*t+1], v2 = cnt[4*t+2], v3 = cnt[4*t+3];
  int s0 = v0, s1 = s0 + v1, s2 = s1 + v2, s3 = s2 + v3;
  sums[t] = s3;
  __syncthreads();
  for (int off = 1; off < 1024; off <<= 1) {
    int x = (t >= off) ? sums[t - off] : 0;
    __syncthreads();
    sums[t] += x;
    __syncthreads();
  }
  int base = (t > 0) ? sums[t - 1] : 0;
  if (t == 0) rowptr[0] = 0;
  rowptr[4*t+1] = base + s0;
  rowptr[4*t+2] = base + s1;
  rowptr[4*t+3] = base + s2;
  rowptr[4*t+4] = base + s3;
}

__global__ void k_fill(const int* __restrict__ src, const int* __restrict__ dst,
                       const float* __restrict__ dinv, const int* __restrict__ rowptr,
                       int* __restrict__ fill, int* __restrict__ col,
                       float* __restrict__ wv) {
  int e = blockIdx.x * blockDim.x + threadIdx.x;
  if (e >= N_EDGES) return;
  int s = src[e], d = dst[e];
  int p = rowptr[d] + atomicAdd(&fill[d], 1);
  col[p] = s;
  wv[p]  = dinv[s] * dinv[d];
}

// ---------------- SpMM: Acomb = A_hat @ [X1 | X2] ----------------
// one wave per (b,n) node; lane = feature; chunks of 64 features.
__global__ __launch_bounds__(256) void k_spmm(
    const int* __restrict__ rowptr, const int* __restrict__ col,
    const float* __restrict__ wv, const float* __restrict__ dinv,
    const float* __restrict__ X1, long bs1, int F1,
    const float* __restrict__ X2, long bs2, int F2,
    float* __restrict__ out) {
  int wid  = threadIdx.x >> 6;
  int lane = threadIdx.x & 63;
  int node = blockIdx.x * 4 + wid;               // [0, M)
  int b = node >> 12, n = node & (N_NODES - 1);
  int nch1 = F1 >> 6;
  int ncht = (F1 + F2) >> 6;                     // 3 or 4
  const float* base1 = X1 + (long)b * bs1;
  const float* base2 = X2 + (long)b * bs2;
  float acc[4] = {0.f, 0.f, 0.f, 0.f};
  int rs = rowptr[n], re = rowptr[n + 1];
  int   cc = 0; float w = 0.f;
  if (rs < re) { cc = col[rs]; w = wv[rs]; }
  for (int e = rs; e < re; ++e) {
    int cur_c = cc; float cur_w = w;
    if (e + 1 < re) { cc = col[e + 1]; w = wv[e + 1]; }   // prefetch next edge
    const float* p1 = base1 + (long)cur_c * F1;
    const float* p2 = base2 + (long)cur_c * F2;
    #pragma unroll
    for (int ch = 0; ch < 4; ++ch) {
      if (ch < nch1)      acc[ch] += cur_w * p1[ch * 64 + lane];
      else if (ch < ncht) acc[ch] += cur_w * p2[(ch - nch1) * 64 + lane];
    }
  }
  float dn = dinv[n];
  float sw = 2.0f * dn * dn;                     // improved self-loop weight
  const float* q1 = base1 + (long)n * F1;
  const float* q2 = base2 + (long)n * F2;
  #pragma unroll
  for (int ch = 0; ch < 4; ++ch) {
    if (ch < nch1)      acc[ch] += sw * q1[ch * 64 + lane];
    else if (ch < ncht) acc[ch] += sw * q2[(ch - nch1) * 64 + lane];
  }
  float* op = out + (long)node * (F1 + F2);
  #pragma unroll
  for (int ch = 0; ch < 4; ++ch)
    if (ch < ncht) op[ch * 64 + lane] = acc[ch];
}

// ---------------- fused GEMM (M x K @ K x 512) + LSTM pointwise ----------------
// block = 256 threads: c = tid&127 (h-feature), rg = tid>>7 (2 groups of 16 rows)
// each thread owns gate columns {c, c+128, c+256, c+384} for 16 rows -> LSTM in-register
template<int K>
__global__ __launch_bounds__(256) void k_gemm_lstm(
    const float* __restrict__ A, const float* __restrict__ W,
    const float* __restrict__ bias,
    float* __restrict__ hbuf, float* __restrict__ cbuf,
    float* __restrict__ out2, int t) {
  __shared__ float At[K][36];                    // transposed A tile, padded
  int tid = threadIdx.x;
  int m0  = blockIdx.x * 32;
  for (int i = tid; i < 32 * K; i += 256) {
    int r = i / K, k = i - r * K;
    At[k][r] = A[(long)(m0 + r) * K + k];
  }
  __syncthreads();
  int c  = tid & 127;
  int rg = tid >> 7;
  float acc0[16], acc1[16], acc2[16], acc3[16];
  #pragma unroll
  for (int r = 0; r < 16; ++r) { acc0[r] = 0.f; acc1[r] = 0.f; acc2[r] = 0.f; acc3[r] = 0.f; }
  const float* Wc = W + c;
  #pragma unroll 4
  for (int k = 0; k < K; ++k) {
    float w0 = Wc[k * 512 + 0];
    float w1 = Wc[k * 512 + 128];
    float w2 = Wc[k * 512 + 256];
    float w3 = Wc[k * 512 + 384];
    const float4* ap = reinterpret_cast<const float4*>(&At[k][rg * 16]);
    float4 a0 = ap[0], a1 = ap[1], a2 = ap[2], a3 = ap[3];
    float ar[16] = {a0.x,a0.y,a0.z,a0.w, a1.x,a1.y,a1.z,a1.w,
                    a2.x,a2.y,a2.z,a2.w, a3.x,a3.y,a3.z,a3.w};
    #pragma unroll
    for (int r = 0; r < 16; ++r) {
      acc0[r] = fmaf(ar[r], w0, acc0[r]);
      acc1[r] = fmaf(ar[r], w1, acc1[r]);
      acc2[r] = fmaf(ar[r], w2, acc2[r]);
      acc3[r] = fmaf(ar[r], w3, acc3[r]);
    }
  }
  float bi = bias[c], bf = bias[c + 128], bo = bias[c + 256], bg = bias[c + 384];
  #pragma unroll
  for (int r = 0; r < 16; ++r) {
    int m = m0 + rg * 16 + r;
    float ig = 1.0f / (1.0f + __expf(-(acc0[r] + bi)));
    float fg = 1.0f / (1.0f + __expf(-(acc1[r] + bf)));
    float og = 1.0f / (1.0f + __expf(-(acc2[r] + bo)));
    float gg = tanhf(acc3[r] + bg);
    long idx = (long)m * H + c;
    float cold = cbuf[idx];
    float cn = fg * cold + ig * gg;
    float hn = og * tanhf(cn);
    cbuf[idx] = cn;
    hbuf[idx] = hn;
    if (out2) {
      int bb = m >> 12, nn = m & (N_NODES - 1);
      out2[(((long)bb * T + t) * N_NODES + nn) * H + c] = hn;
    }
  }
}

// ---------------- launch ----------------

extern "C" void kernel_launch(void* const* d_in, const int* in_sizes, int n_in,
                              void* d_out, int out_size, void* d_ws, size_t ws_size,
                              hipStream_t stream) {
  const float* x  = (const float*)d_in[0];
  const float* W0 = (const float*)d_in[1];
  const float* b0 = (const float*)d_in[2];
  const float* W1 = (const float*)d_in[3];
  const float* b1 = (const float*)d_in[4];
  const int*   ei = (const int*)d_in[5];
  const int* srcp = ei;
  const int* dstp = ei + N_EDGES;
  float* out = (float*)d_out;

  char* p = (char*)d_ws;
  auto alloc = [&](size_t bytes) {
    char* r = p;
    p += (bytes + 255) & ~(size_t)255;
    return r;
  };
  int*   cnt    = (int*)  alloc(N_NODES * 4);
  int*   fill   = (int*)  alloc(N_NODES * 4);
  float* dinv   = (float*)alloc(N_NODES * 4);
  int*   rowptr = (int*)  alloc((N_NODES + 1) * 4);
  int*   colc   = (int*)  alloc(N_EDGES * 4);
  float* wv     = (float*)alloc(N_EDGES * 4);
  float* hc     = (float*)alloc((size_t)4 * M * H * 4);   // h0,c0,h1,c1
  float* Acomb  = (float*)alloc((size_t)M * 256 * 4);
  float* h0 = hc;
  float* c0 = hc + (size_t)M * H;
  float* h1 = hc + (size_t)2 * M * H;
  float* c1 = hc + (size_t)3 * M * H;

  hipMemsetAsync(cnt,  0, N_NODES * 4, stream);
  hipMemsetAsync(fill, 0, N_NODES * 4, stream);
  hipMemsetAsync(hc,   0, (size_t)4 * M * H * 4, stream);

  k_count<<<N_EDGES / 256, 256, 0, stream>>>(dstp, cnt);
  k_dinv <<<N_NODES / 256, 256, 0, stream>>>(cnt, dinv);
  k_scan <<<1, 1024, 0, stream>>>(cnt, rowptr);
  k_fill <<<N_EDGES / 256, 256, 0, stream>>>(srcp, dstp, dinv, rowptr, fill, colc, wv);

  for (int t = 0; t < T; ++t) {
    // layer 0: Acomb = A_hat @ [x_t | h0]   (F = 64 + 128 = 192)
    k_spmm<<<M / 4, 256, 0, stream>>>(rowptr, colc, wv, dinv,
        x + (size_t)t * N_NODES * D_INF, (long)T * N_NODES * D_INF, D_INF,
        h0, (long)N_NODES * H, H, Acomb);
    k_gemm_lstm<192><<<M / 32, 256, 0, stream>>>(Acomb, W0, b0, h0, c0, nullptr, t);
    // layer 1: Acomb = A_hat @ [h0_t | h1]  (F = 128 + 128 = 256)
    k_spmm<<<M / 4, 256, 0, stream>>>(rowptr, colc, wv, dinv,
        h0, (long)N_NODES * H, H, h1, (long)N_NODES * H, H, Acomb);
    k_gemm_lstm<256><<<M / 32, 256, 0, stream>>>(Acomb, W1, b1, h1, c1, out, t);
  }
}

// Round 2
// 1657.759 us; speedup vs baseline: 2.1597x; 2.1597x over previous
//
#include <hip/hip_runtime.h>
#include <math.h>

constexpr int N_NODES = 4096;
constexpr int N_EDGES = 65536;
constexpr int D_INF   = 64;
constexpr int H       = 128;
constexpr int T       = 8;
constexpr int B       = 8;
constexpr int M       = B * N_NODES;   // 32768 rows per GEMM

typedef __attribute__((ext_vector_type(8))) short bf16x8;
typedef __attribute__((ext_vector_type(4))) float f32x4;

__device__ inline unsigned short f2bf(float x) {
  unsigned int u = __float_as_uint(x);
  unsigned int r = (u + 0x7fffu + ((u >> 16) & 1u)) >> 16;
  return (unsigned short)r;
}
__device__ inline float bf2f(unsigned short b) {
  return __uint_as_float((unsigned int)b << 16);
}

// ---------------- CSR build ----------------

__global__ void k_count(const int* __restrict__ dst, int* __restrict__ cnt) {
  int e = blockIdx.x * blockDim.x + threadIdx.x;
  if (e < N_EDGES) atomicAdd(&cnt[dst[e]], 1);
}

__global__ void k_dinv(const int* __restrict__ cnt, float* __restrict__ dinv) {
  int n = blockIdx.x * blockDim.x + threadIdx.x;
  if (n < N_NODES) dinv[n] = 1.0f / sqrtf((float)cnt[n] + 2.0f);
}

__global__ void k_scan(const int* __restrict__ cnt, int* __restrict__ rowptr) {
  __shared__ int sums[1024];
  int t = threadIdx.x;
  int v0 = cnt[4*t+0], v1 = cnt[4*t+1], v2 = cnt[4*t+2], v3 = cnt[4*t+3];
  int s0 = v0, s1 = s0 + v1, s2 = s1 + v2, s3 = s2 + v3;
  sums[t] = s3;
  __syncthreads();
  for (int off = 1; off < 1024; off <<= 1) {
    int x = (t >= off) ? sums[t - off] : 0;
    __syncthreads();
    sums[t] += x;
    __syncthreads();
  }
  int base = (t > 0) ? sums[t - 1] : 0;
  if (t == 0) rowptr[0] = 0;
  rowptr[4*t+1] = base + s0;
  rowptr[4*t+2] = base + s1;
  rowptr[4*t+3] = base + s2;
  rowptr[4*t+4] = base + s3;
}

__global__ void k_fill(const int* __restrict__ src, const int* __restrict__ dst,
                       const float* __restrict__ dinv, const int* __restrict__ rowptr,
                       int* __restrict__ fill, int* __restrict__ col,
                       float* __restrict__ wv) {
  int e = blockIdx.x * blockDim.x + threadIdx.x;
  if (e >= N_EDGES) return;
  int s = src[e], d = dst[e];
  int p = rowptr[d] + atomicAdd(&fill[d], 1);
  col[p] = s;
  wv[p]  = dinv[s] * dinv[d];
}

// ---------------- W pack: gate-interleaved cols + MFMA fragment order + hi/lo ----
__global__ void k_pack(const float* __restrict__ W, unsigned short* __restrict__ Bp,
                       int K) {
  int tid = blockIdx.x * 256 + threadIdx.x;
  if (tid >= K * 64) return;
  int lane = tid & 63;
  int ntg  = (tid >> 6) & 31;
  int kb   = tid >> 11;
  int gate = ntg & 3, fg = ntg >> 2;
  int corig = gate * 128 + fg * 16 + (lane & 15);
  int k0 = kb * 32 + (lane >> 4) * 8;
  long obase = ((long)(kb * 32 + ntg) * 64 + lane) * 8;
  long plane = (long)K * 512;
  #pragma unroll
  for (int j = 0; j < 8; ++j) {
    float v = W[(long)(k0 + j) * 512 + corig];
    unsigned short h = f2bf(v);
    Bp[obase + j]         = h;
    Bp[plane + obase + j] = f2bf(v - bf2f(h));
  }
}

// ---------------- SpMM: [Ah|Al] = split_bf16( A_hat @ [X1 | X2] ) ----------------
template<int F1, int F2>
__global__ __launch_bounds__(256) void k_spmm(
    const int* __restrict__ rowptr, const int* __restrict__ col,
    const float* __restrict__ wv, const float* __restrict__ dinv,
    const float* __restrict__ X1, long bs1,
    const float* __restrict__ X2, long bs2,
    unsigned short* __restrict__ Ah, unsigned short* __restrict__ Al) {
  constexpr int F = F1 + F2;
  int wid  = threadIdx.x >> 6;
  int lane = threadIdx.x & 63;
  int node = blockIdx.x * 4 + wid;
  int b = node >> 12, n = node & (N_NODES - 1);
  int c4 = lane * 4;
  bool act = c4 < F;
  const float* basep = (c4 < F1) ? (X1 + (long)b * bs1 + c4)
                                 : (X2 + (long)b * bs2 + (c4 - F1));
  long str = (c4 < F1) ? (long)F1 : (long)F2;
  f32x4 acc = {0.f, 0.f, 0.f, 0.f};
  int rs = rowptr[n], re = rowptr[n + 1];
  int e = rs;
  for (; e + 2 <= re; e += 2) {
    int c0 = col[e], c1 = col[e + 1];
    float w0 = wv[e], w1 = wv[e + 1];
    if (act) {
      f32x4 v0 = *(const f32x4*)(basep + (long)c0 * str);
      f32x4 v1 = *(const f32x4*)(basep + (long)c1 * str);
      acc += w0 * v0;
      acc += w1 * v1;
    }
  }
  if (e < re && act) {
    f32x4 v0 = *(const f32x4*)(basep + (long)col[e] * str);
    acc += wv[e] * v0;
  }
  float dn = dinv[n];
  float sw = 2.0f * dn * dn;
  if (act) {
    f32x4 v = *(const f32x4*)(basep + (long)n * str);
    acc += sw * v;
    unsigned short hs[4], ls[4];
    #pragma unroll
    for (int j = 0; j < 4; ++j) {
      unsigned short h = f2bf(acc[j]);
      hs[j] = h;
      ls[j] = f2bf(acc[j] - bf2f(h));
    }
    uint2 hp, lp;
    hp.x = (unsigned)hs[0] | ((unsigned)hs[1] << 16);
    hp.y = (unsigned)hs[2] | ((unsigned)hs[3] << 16);
    lp.x = (unsigned)ls[0] | ((unsigned)ls[1] << 16);
    lp.y = (unsigned)ls[2] | ((unsigned)ls[3] << 16);
    *(uint2*)(Ah + (long)node * F + c4) = hp;
    *(uint2*)(Al + (long)node * F + c4) = lp;
  }
}

// ---------------- MFMA GEMM (split-bf16, 3-term) + fused LSTM ----------------
template<int K>
__global__ __launch_bounds__(256) void k_gemm_lstm(
    const unsigned short* __restrict__ Ah, const unsigned short* __restrict__ Al,
    const unsigned short* __restrict__ Bp, const float* __restrict__ bias,
    float* __restrict__ hbuf, float* __restrict__ cbuf,
    float* __restrict__ out2, int t) {
  constexpr int KB = K / 32;
  int lane = threadIdx.x & 63;
  int w    = threadIdx.x >> 6;
  int g    = blockIdx.x * 4 + w;
  int mblk = g >> 3;                   // 1024 row-blocks of 32
  int fg   = g & 7;                    // 8 feature groups of 16
  int m0   = mblk * 32;
  int l15 = lane & 15, lq = lane >> 4;

  const unsigned short* a0h = Ah + (long)(m0 + l15) * K + lq * 8;
  const unsigned short* a0l = Al + (long)(m0 + l15) * K + lq * 8;
  const unsigned short* bh  = Bp + (long)(fg * 4) * 512 + lane * 8;
  const unsigned short* bl  = bh + (long)K * 512;

  f32x4 acc[2][4];
  #pragma unroll
  for (int mt = 0; mt < 2; ++mt)
    #pragma unroll
    for (int gt = 0; gt < 4; ++gt)
      acc[mt][gt] = (f32x4){0.f, 0.f, 0.f, 0.f};

  #pragma unroll
  for (int kb = 0; kb < KB; ++kb) {
    bf16x8 AH0 = *(const bf16x8*)(a0h + kb * 32);
    bf16x8 AH1 = *(const bf16x8*)(a0h + 16 * K + kb * 32);
    bf16x8 AL0 = *(const bf16x8*)(a0l + kb * 32);
    bf16x8 AL1 = *(const bf16x8*)(a0l + 16 * K + kb * 32);
    bf16x8 BH[4], BL[4];
    #pragma unroll
    for (int gt = 0; gt < 4; ++gt) {
      BH[gt] = *(const bf16x8*)(bh + ((long)kb * 32 + gt) * 512);
      BL[gt] = *(const bf16x8*)(bl + ((long)kb * 32 + gt) * 512);
    }
    #pragma unroll
    for (int gt = 0; gt < 4; ++gt) {
      acc[0][gt] = __builtin_amdgcn_mfma_f32_16x16x32_bf16(AH0, BH[gt], acc[0][gt], 0, 0, 0);
      acc[1][gt] = __builtin_amdgcn_mfma_f32_16x16x32_bf16(AH1, BH[gt], acc[1][gt], 0, 0, 0);
      acc[0][gt] = __builtin_amdgcn_mfma_f32_16x16x32_bf16(AL0, BH[gt], acc[0][gt], 0, 0, 0);
      acc[1][gt] = __builtin_amdgcn_mfma_f32_16x16x32_bf16(AL1, BH[gt], acc[1][gt], 0, 0, 0);
      acc[0][gt] = __builtin_amdgcn_mfma_f32_16x16x32_bf16(AH0, BL[gt], acc[0][gt], 0, 0, 0);
      acc[1][gt] = __builtin_amdgcn_mfma_f32_16x16x32_bf16(AH1, BL[gt], acc[1][gt], 0, 0, 0);
    }
  }

  int f = fg * 16 + l15;
  float bi = bias[f], bff = bias[128 + f], bo = bias[256 + f], bg = bias[384 + f];
  #pragma unroll
  for (int mt = 0; mt < 2; ++mt) {
    #pragma unroll
    for (int r = 0; r < 4; ++r) {
      int m = m0 + mt * 16 + lq * 4 + r;
      float vi = 1.0f / (1.0f + __expf(-(acc[mt][0][r] + bi)));
      float vf = 1.0f / (1.0f + __expf(-(acc[mt][1][r] + bff)));
      float vo = 1.0f / (1.0f + __expf(-(acc[mt][2][r] + bo)));
      float vg = tanhf(acc[mt][3][r] + bg);
      long idx = (long)m * H + f;
      float cn = vf * cbuf[idx] + vi * vg;
      float hn = vo * tanhf(cn);
      cbuf[idx] = cn;
      hbuf[idx] = hn;
      if (out2) {
        int bb = m >> 12, nn = m & (N_NODES - 1);
        out2[(((long)bb * T + t) * N_NODES + nn) * H + f] = hn;
      }
    }
  }
}

// ---------------- launch ----------------

extern "C" void kernel_launch(void* const* d_in, const int* in_sizes, int n_in,
                              void* d_out, int out_size, void* d_ws, size_t ws_size,
                              hipStream_t stream) {
  const float* x  = (const float*)d_in[0];
  const float* W0 = (const float*)d_in[1];
  const float* b0 = (const float*)d_in[2];
  const float* W1 = (const float*)d_in[3];
  const float* b1 = (const float*)d_in[4];
  const int*   ei = (const int*)d_in[5];
  const int* srcp = ei;
  const int* dstp = ei + N_EDGES;
  float* out = (float*)d_out;

  char* p = (char*)d_ws;
  auto alloc = [&](size_t bytes) {
    char* r = p;
    p += (bytes + 255) & ~(size_t)255;
    return r;
  };
  int*   cnt    = (int*)  alloc(N_NODES * 4);
  int*   fill   = (int*)  alloc(N_NODES * 4);
  float* dinv   = (float*)alloc(N_NODES * 4);
  int*   rowptr = (int*)  alloc((N_NODES + 1) * 4);
  int*   colc   = (int*)  alloc(N_EDGES * 4);
  float* wv     = (float*)alloc(N_EDGES * 4);
  float* hc     = (float*)alloc((size_t)4 * M * H * 4);     // h0,c0,h1,c1 fp32
  unsigned short* Ah  = (unsigned short*)alloc((size_t)M * 256 * 2);
  unsigned short* Al  = (unsigned short*)alloc((size_t)M * 256 * 2);
  unsigned short* Bp0 = (unsigned short*)alloc((size_t)192 * 512 * 2 * 2);
  unsigned short* Bp1 = (unsigned short*)alloc((size_t)256 * 512 * 2 * 2);
  float* h0 = hc;
  float* c0 = hc + (size_t)M * H;
  float* h1 = hc + (size_t)2 * M * H;
  float* c1 = hc + (size_t)3 * M * H;

  hipMemsetAsync(cnt,  0, N_NODES * 4, stream);
  hipMemsetAsync(fill, 0, N_NODES * 4, stream);
  hipMemsetAsync(hc,   0, (size_t)4 * M * H * 4, stream);

  k_count<<<N_EDGES / 256, 256, 0, stream>>>(dstp, cnt);
  k_dinv <<<N_NODES / 256, 256, 0, stream>>>(cnt, dinv);
  k_scan <<<1, 1024, 0, stream>>>(cnt, rowptr);
  k_fill <<<N_EDGES / 256, 256, 0, stream>>>(srcp, dstp, dinv, rowptr, fill, colc, wv);
  k_pack <<<(192 * 64 + 255) / 256, 256, 0, stream>>>(W0, Bp0, 192);
  k_pack <<<(256 * 64 + 255) / 256, 256, 0, stream>>>(W1, Bp1, 256);

  for (int t = 0; t < T; ++t) {
    // layer 0: A = A_hat @ [x_t | h0]   (K = 192)
    k_spmm<D_INF, H><<<M / 4, 256, 0, stream>>>(rowptr, colc, wv, dinv,
        x + (size_t)t * N_NODES * D_INF, (long)T * N_NODES * D_INF,
        h0, (long)N_NODES * H, Ah, Al);
    k_gemm_lstm<192><<<2048, 256, 0, stream>>>(Ah, Al, Bp0, b0, h0, c0, nullptr, t);
    // layer 1: A = A_hat @ [h0_t | h1]  (K = 256)
    k_spmm<H, H><<<M / 4, 256, 0, stream>>>(rowptr, colc, wv, dinv,
        h0, (long)N_NODES * H, h1, (long)N_NODES * H, Ah, Al);
    k_gemm_lstm<256><<<2048, 256, 0, stream>>>(Ah, Al, Bp1, b1, h1, c1, out, t);
  }
}

// Round 3
// 1521.664 us; speedup vs baseline: 2.3529x; 1.0894x over previous
//
#include <hip/hip_runtime.h>
#include <math.h>

constexpr int N_NODES = 4096;
constexpr int N_EDGES = 65536;
constexpr int D_INF   = 64;
constexpr int H       = 128;
constexpr int T       = 8;
constexpr int B       = 8;
constexpr int M       = B * N_NODES;   // 32768 rows per GEMM

typedef __attribute__((ext_vector_type(8))) short bf16x8;
typedef __attribute__((ext_vector_type(4))) float f32x4;

__device__ inline unsigned short f2bf(float x) {
  unsigned int u = __float_as_uint(x);
  unsigned int r = (u + 0x7fffu + ((u >> 16) & 1u)) >> 16;
  return (unsigned short)r;
}
__device__ inline float bf2f(unsigned short b) {
  return __uint_as_float((unsigned int)b << 16);
}

// ---------------- CSR build ----------------

__global__ void k_count(const int* __restrict__ dst, int* __restrict__ cnt) {
  int e = blockIdx.x * blockDim.x + threadIdx.x;
  if (e < N_EDGES) atomicAdd(&cnt[dst[e]], 1);
}

__global__ void k_dinv(const int* __restrict__ cnt, float* __restrict__ dinv) {
  int n = blockIdx.x * blockDim.x + threadIdx.x;
  if (n < N_NODES) dinv[n] = 1.0f / sqrtf((float)cnt[n] + 2.0f);
}

__global__ void k_scan(const int* __restrict__ cnt, int* __restrict__ rowptr) {
  __shared__ int sums[1024];
  int t = threadIdx.x;
  int v0 = cnt[4*t+0], v1 = cnt[4*t+1], v2 = cnt[4*t+2], v3 = cnt[4*t+3];
  int s0 = v0, s1 = s0 + v1, s2 = s1 + v2, s3 = s2 + v3;
  sums[t] = s3;
  __syncthreads();
  for (int off = 1; off < 1024; off <<= 1) {
    int x = (t >= off) ? sums[t - off] : 0;
    __syncthreads();
    sums[t] += x;
    __syncthreads();
  }
  int base = (t > 0) ? sums[t - 1] : 0;
  if (t == 0) rowptr[0] = 0;
  rowptr[4*t+1] = base + s0;
  rowptr[4*t+2] = base + s1;
  rowptr[4*t+3] = base + s2;
  rowptr[4*t+4] = base + s3;
}

__global__ void k_fill(const int* __restrict__ src, const int* __restrict__ dst,
                       const float* __restrict__ dinv, const int* __restrict__ rowptr,
                       int* __restrict__ fill, int* __restrict__ col,
                       float* __restrict__ wv) {
  int e = blockIdx.x * blockDim.x + threadIdx.x;
  if (e >= N_EDGES) return;
  int s = src[e], d = dst[e];
  int p = rowptr[d] + atomicAdd(&fill[d], 1);
  col[p] = s;
  wv[p]  = dinv[s] * dinv[d];
}

// ---------------- W pack: gate-interleaved cols + MFMA fragment order + hi/lo ----
__global__ void k_pack(const float* __restrict__ W, unsigned short* __restrict__ Bp,
                       int K) {
  int tid = blockIdx.x * 256 + threadIdx.x;
  if (tid >= K * 64) return;
  int lane = tid & 63;
  int ntg  = (tid >> 6) & 31;
  int kb   = tid >> 11;
  int gate = ntg & 3, fg = ntg >> 2;
  int corig = gate * 128 + fg * 16 + (lane & 15);
  int k0 = kb * 32 + (lane >> 4) * 8;
  long obase = ((long)(kb * 32 + ntg) * 64 + lane) * 8;
  long plane = (long)K * 512;
  #pragma unroll
  for (int j = 0; j < 8; ++j) {
    float v = W[(long)(k0 + j) * 512 + corig];
    unsigned short h = f2bf(v);
    Bp[obase + j]         = h;
    Bp[plane + obase + j] = f2bf(v - bf2f(h));
  }
}

// ---------------- SpMM: [Ah|Al] = split_bf16( A_hat @ [X1 | X2] ) ----------------
// one wave per (b,n) node; lane owns 4 consecutive features (float4 gather).
// XCD swizzle: batch b -> XCD b (8 batches, 8 XCDs, round-robin dispatch).
template<int F1, int F2>
__global__ __launch_bounds__(256) void k_spmm(
    const int* __restrict__ rowptr, const int* __restrict__ col,
    const float* __restrict__ wv, const float* __restrict__ dinv,
    const float* __restrict__ X1, long bs1,
    const float* __restrict__ X2, long bs2,
    unsigned short* __restrict__ Ah, unsigned short* __restrict__ Al) {
  constexpr int F = F1 + F2;
  int wid  = threadIdx.x >> 6;
  int lane = threadIdx.x & 63;
  int j    = blockIdx.x;                         // 8192 blocks
  int obk  = (j & 7) * 1024 + (j >> 3);          // XCD j%8 gets batch j%8
  int node = obk * 4 + wid;
  int b = node >> 12, n = node & (N_NODES - 1);
  int c4 = lane * 4;
  bool act = c4 < F;
  const float* basep = (c4 < F1) ? (X1 + (long)b * bs1 + c4)
                                 : (X2 + (long)b * bs2 + (c4 - F1));
  long str = (c4 < F1) ? (long)F1 : (long)F2;
  f32x4 acc = {0.f, 0.f, 0.f, 0.f};
  int rs = rowptr[n], re = rowptr[n + 1];
  int e = rs;
  for (; e + 2 <= re; e += 2) {
    int c0 = col[e], c1 = col[e + 1];
    float w0 = wv[e], w1 = wv[e + 1];
    if (act) {
      f32x4 v0 = *(const f32x4*)(basep + (long)c0 * str);
      f32x4 v1 = *(const f32x4*)(basep + (long)c1 * str);
      acc += w0 * v0;
      acc += w1 * v1;
    }
  }
  if (e < re && act) {
    f32x4 v0 = *(const f32x4*)(basep + (long)col[e] * str);
    acc += wv[e] * v0;
  }
  float dn = dinv[n];
  float sw = 2.0f * dn * dn;
  if (act) {
    f32x4 v = *(const f32x4*)(basep + (long)n * str);
    acc += sw * v;
    unsigned short hs[4], ls[4];
    #pragma unroll
    for (int jj = 0; jj < 4; ++jj) {
      unsigned short h = f2bf(acc[jj]);
      hs[jj] = h;
      ls[jj] = f2bf(acc[jj] - bf2f(h));
    }
    uint2 hp, lp;
    hp.x = (unsigned)hs[0] | ((unsigned)hs[1] << 16);
    hp.y = (unsigned)hs[2] | ((unsigned)hs[3] << 16);
    lp.x = (unsigned)ls[0] | ((unsigned)ls[1] << 16);
    lp.y = (unsigned)ls[2] | ((unsigned)ls[3] << 16);
    *(uint2*)(Ah + (long)node * F + c4) = hp;
    *(uint2*)(Al + (long)node * F + c4) = lp;
  }
}

// ---------------- MFMA GEMM (split-bf16, 3-term) + fused LSTM ----------------
// block = 4 waves = one 32-row tile x all 512 cols (each wave: 2 fg groups).
// Ah+Al staged ONCE into LDS in fragment-linear order -> conflict-free ds_read_b128.
template<int K>
__global__ __launch_bounds__(256, 3) void k_gemm_lstm(
    const unsigned short* __restrict__ Ah, const unsigned short* __restrict__ Al,
    const unsigned short* __restrict__ Bp, const float* __restrict__ bias,
    float* __restrict__ hbuf, float* __restrict__ cbuf,
    float* __restrict__ out2, int t) {
  constexpr int KB = K / 32;
  __shared__ __align__(16) unsigned short At[4 * KB * 64 * 8];  // 24/32 KB
  int tid  = threadIdx.x;
  int j    = blockIdx.x;                          // 1024 blocks
  int mblk = (j & 7) * 128 + (j >> 3);            // XCD-align with producer batch
  int m0   = mblk * 32;
  int lane = tid & 63;
  int w    = tid >> 6;

  // stage: chunk = ((pm*KB + kb)*64 + lane), pm = plane*2 + mt
  constexpr int NCH = 4 * KB * 64;
  #pragma unroll
  for (int it = 0; it < NCH / 256; ++it) {
    int chunk = it * 256 + tid;
    int cl = chunk & 63;
    int t1 = chunk >> 6;
    int kb = t1 % KB;
    int pm = t1 / KB;
    const unsigned short* sp = (pm >= 2 ? Al : Ah)
        + (long)(m0 + (pm & 1) * 16 + (cl & 15)) * K + kb * 32 + (cl >> 4) * 8;
    *(bf16x8*)(At + (long)chunk * 8) = *(const bf16x8*)sp;
  }
  __syncthreads();

  int fgb = w * 2;                                // wave covers fg = fgb, fgb+1
  const unsigned short* bh = Bp + (long)(fgb * 4) * 512 + lane * 8;
  const unsigned short* bl = bh + (long)K * 512;

  f32x4 acc[2][2][4];
  #pragma unroll
  for (int ff = 0; ff < 2; ++ff)
    #pragma unroll
    for (int mt = 0; mt < 2; ++mt)
      #pragma unroll
      for (int gt = 0; gt < 4; ++gt)
        acc[ff][mt][gt] = (f32x4){0.f, 0.f, 0.f, 0.f};

  #pragma unroll 2
  for (int kb = 0; kb < KB; ++kb) {
    bf16x8 AF[4];
    #pragma unroll
    for (int pm = 0; pm < 4; ++pm)
      AF[pm] = *(const bf16x8*)(At + ((pm * KB + kb) * 64 + lane) * 8);
    #pragma unroll
    for (int ff = 0; ff < 2; ++ff) {
      bf16x8 BH[4], BL[4];
      #pragma unroll
      for (int gt = 0; gt < 4; ++gt) {
        BH[gt] = *(const bf16x8*)(bh + (long)ff * 2048 + ((long)kb * 32 + gt) * 512);
        BL[gt] = *(const bf16x8*)(bl + (long)ff * 2048 + ((long)kb * 32 + gt) * 512);
      }
      #pragma unroll
      for (int gt = 0; gt < 4; ++gt) {
        acc[ff][0][gt] = __builtin_amdgcn_mfma_f32_16x16x32_bf16(AF[0], BH[gt], acc[ff][0][gt], 0, 0, 0);
        acc[ff][1][gt] = __builtin_amdgcn_mfma_f32_16x16x32_bf16(AF[1], BH[gt], acc[ff][1][gt], 0, 0, 0);
        acc[ff][0][gt] = __builtin_amdgcn_mfma_f32_16x16x32_bf16(AF[2], BH[gt], acc[ff][0][gt], 0, 0, 0);
        acc[ff][1][gt] = __builtin_amdgcn_mfma_f32_16x16x32_bf16(AF[3], BH[gt], acc[ff][1][gt], 0, 0, 0);
        acc[ff][0][gt] = __builtin_amdgcn_mfma_f32_16x16x32_bf16(AF[0], BL[gt], acc[ff][0][gt], 0, 0, 0);
        acc[ff][1][gt] = __builtin_amdgcn_mfma_f32_16x16x32_bf16(AF[1], BL[gt], acc[ff][1][gt], 0, 0, 0);
      }
    }
  }

  int l15 = lane & 15, lq = lane >> 4;
  #pragma unroll
  for (int ff = 0; ff < 2; ++ff) {
    int f = (fgb + ff) * 16 + l15;
    float bi = bias[f], bff = bias[128 + f], bo = bias[256 + f], bg = bias[384 + f];
    #pragma unroll
    for (int mt = 0; mt < 2; ++mt) {
      #pragma unroll
      for (int r = 0; r < 4; ++r) {
        int m = m0 + mt * 16 + lq * 4 + r;
        float vi = 1.0f / (1.0f + __expf(-(acc[ff][mt][0][r] + bi)));
        float vf = 1.0f / (1.0f + __expf(-(acc[ff][mt][1][r] + bff)));
        float vo = 1.0f / (1.0f + __expf(-(acc[ff][mt][2][r] + bo)));
        float vg = tanhf(acc[ff][mt][3][r] + bg);
        long idx = (long)m * H + f;
        float cn = vf * cbuf[idx] + vi * vg;
        float hn = vo * tanhf(cn);
        cbuf[idx] = cn;
        hbuf[idx] = hn;
        if (out2) {
          int bb = m >> 12, nn = m & (N_NODES - 1);
          out2[(((long)bb * T + t) * N_NODES + nn) * H + f] = hn;
        }
      }
    }
  }
}

// ---------------- launch ----------------

extern "C" void kernel_launch(void* const* d_in, const int* in_sizes, int n_in,
                              void* d_out, int out_size, void* d_ws, size_t ws_size,
                              hipStream_t stream) {
  const float* x  = (const float*)d_in[0];
  const float* W0 = (const float*)d_in[1];
  const float* b0 = (const float*)d_in[2];
  const float* W1 = (const float*)d_in[3];
  const float* b1 = (const float*)d_in[4];
  const int*   ei = (const int*)d_in[5];
  const int* srcp = ei;
  const int* dstp = ei + N_EDGES;
  float* out = (float*)d_out;

  char* p = (char*)d_ws;
  auto alloc = [&](size_t bytes) {
    char* r = p;
    p += (bytes + 255) & ~(size_t)255;
    return r;
  };
  int*   cnt    = (int*)  alloc(N_NODES * 4);
  int*   fill   = (int*)  alloc(N_NODES * 4);
  float* dinv   = (float*)alloc(N_NODES * 4);
  int*   rowptr = (int*)  alloc((N_NODES + 1) * 4);
  int*   colc   = (int*)  alloc(N_EDGES * 4);
  float* wv     = (float*)alloc(N_EDGES * 4);
  float* hc     = (float*)alloc((size_t)4 * M * H * 4);     // h0,c0,h1,c1 fp32
  unsigned short* Ah  = (unsigned short*)alloc((size_t)M * 256 * 2);
  unsigned short* Al  = (unsigned short*)alloc((size_t)M * 256 * 2);
  unsigned short* Bp0 = (unsigned short*)alloc((size_t)192 * 512 * 2 * 2);
  unsigned short* Bp1 = (unsigned short*)alloc((size_t)256 * 512 * 2 * 2);
  float* h0 = hc;
  float* c0 = hc + (size_t)M * H;
  float* h1 = hc + (size_t)2 * M * H;
  float* c1 = hc + (size_t)3 * M * H;

  hipMemsetAsync(cnt,  0, N_NODES * 4, stream);
  hipMemsetAsync(fill, 0, N_NODES * 4, stream);
  hipMemsetAsync(hc,   0, (size_t)4 * M * H * 4, stream);

  k_count<<<N_EDGES / 256, 256, 0, stream>>>(dstp, cnt);
  k_dinv <<<N_NODES / 256, 256, 0, stream>>>(cnt, dinv);
  k_scan <<<1, 1024, 0, stream>>>(cnt, rowptr);
  k_fill <<<N_EDGES / 256, 256, 0, stream>>>(srcp, dstp, dinv, rowptr, fill, colc, wv);
  k_pack <<<(192 * 64 + 255) / 256, 256, 0, stream>>>(W0, Bp0, 192);
  k_pack <<<(256 * 64 + 255) / 256, 256, 0, stream>>>(W1, Bp1, 256);

  for (int t = 0; t < T; ++t) {
    // layer 0: A = A_hat @ [x_t | h0]   (K = 192)
    k_spmm<D_INF, H><<<M / 4, 256, 0, stream>>>(rowptr, colc, wv, dinv,
        x + (size_t)t * N_NODES * D_INF, (long)T * N_NODES * D_INF,
        h0, (long)N_NODES * H, Ah, Al);
    k_gemm_lstm<192><<<1024, 256, 0, stream>>>(Ah, Al, Bp0, b0, h0, c0, nullptr, t);
    // layer 1: A = A_hat @ [h0_t | h1]  (K = 256)
    k_spmm<H, H><<<M / 4, 256, 0, stream>>>(rowptr, colc, wv, dinv,
        h0, (long)N_NODES * H, h1, (long)N_NODES * H, Ah, Al);
    k_gemm_lstm<256><<<1024, 256, 0, stream>>>(Ah, Al, Bp1, b1, h1, c1, out, t);
  }
}